// Round 1
// baseline (257.152 us; speedup 1.0000x reference)
//
#include <hip/hip_runtime.h>
#include <stdint.h>

#define N_NODES 500000
#define IN_DIM  256
#define PROJ    64
#define NBITS   18
#define NB      (1u << NBITS)       // 262144 bins
#define SHIFT   (32 - NBITS)        // 14
#define SCAN_BLK   256
#define SCAN_ELEMS 1024             // bins per scan block
#define SCAN_NBLK  (NB / SCAN_ELEMS) // 256

// order-preserving float -> uint32 key (bijective)
__device__ __forceinline__ uint32_t f2k(float f) {
    uint32_t u = __float_as_uint(f);
    return u ^ (uint32_t)(((int32_t)u >> 31) | 0x80000000);
}
__device__ __forceinline__ float k2f(uint32_t k) {
    uint32_t u = (k & 0x80000000u) ? (k ^ 0x80000000u) : ~k;
    return __uint_as_float(u);
}

// K0: wbar[t] = mean over 64 rows of W[j][t]   (W is [64][256])
__global__ void k_wbar(const float* __restrict__ W, float* __restrict__ wbar) {
    int t = threadIdx.x;  // 256 threads, 1 block
    float s = 0.f;
    for (int j = 0; j < PROJ; ++j) s += W[j * IN_DIM + t];
    wbar[t] = s * (1.0f / PROJ);
}

// K1: v[row] = dot(x[row,:], wbar) via one wave per row; emit key + histogram
__global__ __launch_bounds__(256) void k_gemv(const float* __restrict__ x,
                                              const float* __restrict__ wbar,
                                              uint32_t* __restrict__ key,
                                              uint32_t* __restrict__ hist) {
    const int lane = threadIdx.x & 63;
    const long long row = (long long)blockIdx.x * 4 + (threadIdx.x >> 6);
    if (row >= N_NODES) return;
    const float4 xv = *(const float4*)(x + row * IN_DIM + lane * 4);
    const float4 wv = *(const float4*)(wbar + lane * 4);
    float s = xv.x * wv.x + xv.y * wv.y + xv.z * wv.z + xv.w * wv.w;
    #pragma unroll
    for (int o = 32; o >= 1; o >>= 1) s += __shfl_xor(s, o);
    if (lane == 0) {
        uint32_t k = f2k(s);
        key[row] = k;
        atomicAdd(&hist[k >> SHIFT], 1u);
    }
}

// K2a: per-block scan of 1024 bins (256 threads x 4), block total -> bsum
__global__ __launch_bounds__(SCAN_BLK) void k_scan1(uint32_t* __restrict__ hist,
                                                    uint32_t* __restrict__ bsum) {
    __shared__ uint32_t s[SCAN_BLK];
    const int t = threadIdx.x;
    const uint32_t i = blockIdx.x * SCAN_ELEMS + t * 4;
    uint32_t v0 = hist[i], v1 = hist[i + 1], v2 = hist[i + 2], v3 = hist[i + 3];
    uint32_t tsum = v0 + v1 + v2 + v3;
    s[t] = tsum;
    __syncthreads();
    for (int off = 1; off < SCAN_BLK; off <<= 1) {
        uint32_t u = (t >= off) ? s[t - off] : 0u;
        __syncthreads();
        if (t >= off) s[t] += u;
        __syncthreads();
    }
    uint32_t excl = s[t] - tsum;  // exclusive prefix of this thread's 4
    if (t == SCAN_BLK - 1) bsum[blockIdx.x] = s[t];
    hist[i]     = excl;
    hist[i + 1] = excl + v0;
    hist[i + 2] = excl + v0 + v1;
    hist[i + 3] = excl + v0 + v1 + v2;
}

// K2b: exclusive scan of the 256 block sums (single block)
__global__ __launch_bounds__(SCAN_NBLK) void k_scan2(uint32_t* __restrict__ bsum) {
    __shared__ uint32_t s[SCAN_NBLK];
    const int t = threadIdx.x;
    uint32_t v = bsum[t];
    s[t] = v;
    __syncthreads();
    for (int off = 1; off < SCAN_NBLK; off <<= 1) {
        uint32_t u = (t >= off) ? s[t - off] : 0u;
        __syncthreads();
        if (t >= off) s[t] += u;
        __syncthreads();
    }
    bsum[t] = s[t] - v;
}

// K2c: add block offsets; copy base -> wptr; set sentinel base[NB] = N
__global__ __launch_bounds__(SCAN_BLK) void k_scan3(uint32_t* __restrict__ hist,
                                                    const uint32_t* __restrict__ bsum,
                                                    uint32_t* __restrict__ wptr) {
    const uint32_t i = blockIdx.x * SCAN_ELEMS + threadIdx.x * 4;
    const uint32_t add = bsum[blockIdx.x];
    #pragma unroll
    for (int j = 0; j < 4; ++j) {
        uint32_t b = hist[i + j] + add;
        hist[i + j] = b;
        wptr[i + j] = b;
    }
    if (blockIdx.x == 0 && threadIdx.x == 0) hist[NB] = N_NODES;
}

// K3: scatter elements into bin-grouped arrays
__global__ __launch_bounds__(256) void k_scatter(const uint32_t* __restrict__ key,
                                                 uint32_t* __restrict__ wptr,
                                                 uint32_t* __restrict__ gkey,
                                                 uint32_t* __restrict__ gidx) {
    const int i = blockIdx.x * 256 + threadIdx.x;
    if (i >= N_NODES) return;
    uint32_t k = key[i];
    uint32_t p = atomicAdd(&wptr[k >> SHIFT], 1u);
    gkey[p] = k;
    gidx[p] = (uint32_t)i;
}

// K4: per-element in-bin strict-less count -> sorted output + inverse index
__global__ __launch_bounds__(256) void k_rank(const uint32_t* __restrict__ gkey,
                                              const uint32_t* __restrict__ gidx,
                                              const uint32_t* __restrict__ base,
                                              float* __restrict__ out_sorted,
                                              float* __restrict__ out_inv) {
    const int p = blockIdx.x * 256 + threadIdx.x;
    if (p >= N_NODES) return;
    const uint32_t k = gkey[p];
    const uint32_t b = k >> SHIFT;
    const uint32_t s = base[b], e = base[b + 1];
    uint32_t less = 0, eqb = 0;
    for (uint32_t q = s; q < e; ++q) {
        uint32_t k2 = gkey[q];
        less += (k2 < k) ? 1u : 0u;
        eqb  += ((k2 == k) && (q < (uint32_t)p)) ? 1u : 0u;
    }
    out_sorted[s + less + eqb] = k2f(k);          // unique slot (ties broken by grouped pos)
    out_inv[gidx[p]] = (float)(s + less);         // searchsorted-left rank
}

extern "C" void kernel_launch(void* const* d_in, const int* in_sizes, int n_in,
                              void* d_out, int out_size, void* d_ws, size_t ws_size,
                              hipStream_t stream) {
    const float* x = (const float*)d_in[0];   // [500000, 256]
    const float* W = (const float*)d_in[1];   // [64, 256]

    uint32_t* ws32 = (uint32_t*)d_ws;
    float*    wbar = (float*)ws32;              // 256
    uint32_t* key  = ws32 + 256;                // N
    uint32_t* gkey = key  + N_NODES;            // N
    uint32_t* gidx = gkey + N_NODES;            // N
    uint32_t* hist = gidx + N_NODES;            // NB + 1 (becomes base after scan)
    uint32_t* wptr = hist + NB + 1;             // NB
    uint32_t* bsum = wptr + NB;                 // SCAN_NBLK

    float* out_sorted = (float*)d_out;
    float* out_inv    = out_sorted + N_NODES;

    hipMemsetAsync(hist, 0, (NB + 1) * sizeof(uint32_t), stream);
    k_wbar<<<1, 256, 0, stream>>>(W, wbar);
    k_gemv<<<N_NODES / 4, 256, 0, stream>>>(x, wbar, key, hist);
    k_scan1<<<SCAN_NBLK, SCAN_BLK, 0, stream>>>(hist, bsum);
    k_scan2<<<1, SCAN_NBLK, 0, stream>>>(bsum);
    k_scan3<<<SCAN_NBLK, SCAN_BLK, 0, stream>>>(hist, bsum, wptr);
    k_scatter<<<(N_NODES + 255) / 256, 256, 0, stream>>>(key, wptr, gkey, gidx);
    k_rank<<<(N_NODES + 255) / 256, 256, 0, stream>>>(gkey, gidx, hist, out_sorted, out_inv);
}

// Round 2
// 236.891 us; speedup vs baseline: 1.0855x; 1.0855x over previous
//
#include <hip/hip_runtime.h>
#include <stdint.h>

#define N_NODES 500000
#define IN_DIM  256
#define PROJ    64
#define NBITS   18
#define NB      (1u << NBITS)        // 262144 bins
#define SHIFT   (32 - NBITS)         // 14
#define SCAN_BLK   256
#define SCAN_ELEMS 1024              // bins per scan block
#define SCAN_NBLK  (NB / SCAN_ELEMS) // 256
#define ROWS_PER_WAVE 8
#define ROWS_PER_BLK  (ROWS_PER_WAVE * 4)

// order-preserving float -> uint32 key (bijective)
__device__ __forceinline__ uint32_t f2k(float f) {
    uint32_t u = __float_as_uint(f);
    return u ^ (uint32_t)(((int32_t)u >> 31) | 0x80000000);
}
__device__ __forceinline__ float k2f(uint32_t k) {
    uint32_t u = (k & 0x80000000u) ? (k ^ 0x80000000u) : ~k;
    return __uint_as_float(u);
}

// K0: blocks 0..255 zero hist; block 256 computes wbar[t] = mean_j W[j][t]
__global__ __launch_bounds__(256) void k_prep(const float* __restrict__ W,
                                              float* __restrict__ wbar,
                                              uint32_t* __restrict__ hist) {
    const int t = threadIdx.x;
    if (blockIdx.x == SCAN_NBLK) {
        float s = 0.f;
        for (int j = 0; j < PROJ; ++j) s += W[j * IN_DIM + t];
        wbar[t] = s * (1.0f / PROJ);
    } else {
        uint4 z = {0u, 0u, 0u, 0u};
        *(uint4*)(hist + blockIdx.x * SCAN_ELEMS + t * 4) = z;
    }
}

// K1: 8 rows per wave; coalesced 1KB loads, butterfly reduce, lanes 0..7 emit
__global__ __launch_bounds__(256) void k_gemv(const float* __restrict__ x,
                                              const float* __restrict__ wbar,
                                              uint32_t* __restrict__ key,
                                              uint32_t* __restrict__ hist) {
    const int lane = threadIdx.x & 63;
    const int wave = threadIdx.x >> 6;
    const long long base = ((long long)blockIdx.x * 4 + wave) * ROWS_PER_WAVE;
    const float4 wv = *(const float4*)(wbar + lane * 4);
    const float4* xp = (const float4*)(x + base * IN_DIM) + lane;

    float4 v0 = xp[0 * 64], v1 = xp[1 * 64], v2 = xp[2 * 64], v3 = xp[3 * 64];
    float4 v4 = xp[4 * 64], v5 = xp[5 * 64], v6 = xp[6 * 64], v7 = xp[7 * 64];

    float s0 = v0.x * wv.x + v0.y * wv.y + v0.z * wv.z + v0.w * wv.w;
    float s1 = v1.x * wv.x + v1.y * wv.y + v1.z * wv.z + v1.w * wv.w;
    float s2 = v2.x * wv.x + v2.y * wv.y + v2.z * wv.z + v2.w * wv.w;
    float s3 = v3.x * wv.x + v3.y * wv.y + v3.z * wv.z + v3.w * wv.w;
    float s4 = v4.x * wv.x + v4.y * wv.y + v4.z * wv.z + v4.w * wv.w;
    float s5 = v5.x * wv.x + v5.y * wv.y + v5.z * wv.z + v5.w * wv.w;
    float s6 = v6.x * wv.x + v6.y * wv.y + v6.z * wv.z + v6.w * wv.w;
    float s7 = v7.x * wv.x + v7.y * wv.y + v7.z * wv.z + v7.w * wv.w;

    #pragma unroll
    for (int o = 32; o >= 1; o >>= 1) {
        s0 += __shfl_xor(s0, o); s1 += __shfl_xor(s1, o);
        s2 += __shfl_xor(s2, o); s3 += __shfl_xor(s3, o);
        s4 += __shfl_xor(s4, o); s5 += __shfl_xor(s5, o);
        s6 += __shfl_xor(s6, o); s7 += __shfl_xor(s7, o);
    }
    if (lane < ROWS_PER_WAVE) {
        float sv = (lane == 0) ? s0 : (lane == 1) ? s1 : (lane == 2) ? s2 :
                   (lane == 3) ? s3 : (lane == 4) ? s4 : (lane == 5) ? s5 :
                   (lane == 6) ? s6 : s7;
        uint32_t k = f2k(sv);
        key[base + lane] = k;
        atomicAdd(&hist[k >> SHIFT], 1u);
    }
}

// K2a: per-block scan of 1024 bins (256 threads x 4), block total -> bsum
__global__ __launch_bounds__(SCAN_BLK) void k_scan1(uint32_t* __restrict__ hist,
                                                    uint32_t* __restrict__ bsum) {
    __shared__ uint32_t s[SCAN_BLK];
    const int t = threadIdx.x;
    const uint32_t i = blockIdx.x * SCAN_ELEMS + t * 4;
    uint32_t v0 = hist[i], v1 = hist[i + 1], v2 = hist[i + 2], v3 = hist[i + 3];
    uint32_t tsum = v0 + v1 + v2 + v3;
    s[t] = tsum;
    __syncthreads();
    for (int off = 1; off < SCAN_BLK; off <<= 1) {
        uint32_t u = (t >= off) ? s[t - off] : 0u;
        __syncthreads();
        if (t >= off) s[t] += u;
        __syncthreads();
    }
    uint32_t excl = s[t] - tsum;
    if (t == SCAN_BLK - 1) bsum[blockIdx.x] = s[t];
    hist[i]     = excl;
    hist[i + 1] = excl + v0;
    hist[i + 2] = excl + v0 + v1;
    hist[i + 3] = excl + v0 + v1 + v2;
}

// K2b: each block reduces bsum[0..bid), adds to its bins, copies to wptr
__global__ __launch_bounds__(SCAN_BLK) void k_scan23(uint32_t* __restrict__ hist,
                                                     const uint32_t* __restrict__ bsum,
                                                     uint32_t* __restrict__ wptr) {
    __shared__ uint32_t sh[SCAN_BLK];
    const int t = threadIdx.x;
    const int bid = blockIdx.x;
    sh[t] = (t < bid) ? bsum[t] : 0u;
    __syncthreads();
    for (int off = SCAN_BLK / 2; off >= 1; off >>= 1) {
        if (t < off) sh[t] += sh[t + off];
        __syncthreads();
    }
    const uint32_t add = sh[0];
    const uint32_t i = bid * SCAN_ELEMS + t * 4;
    #pragma unroll
    for (int j = 0; j < 4; ++j) {
        uint32_t b = hist[i + j] + add;
        hist[i + j] = b;
        wptr[i + j] = b;
    }
    if (bid == SCAN_NBLK - 1 && t == SCAN_BLK - 1) hist[NB] = N_NODES;
}

// K3: scatter elements into bin-grouped arrays
__global__ __launch_bounds__(256) void k_scatter(const uint32_t* __restrict__ key,
                                                 uint32_t* __restrict__ wptr,
                                                 uint32_t* __restrict__ gkey,
                                                 uint32_t* __restrict__ gidx) {
    const int i = blockIdx.x * 256 + threadIdx.x;
    if (i >= N_NODES) return;
    uint32_t k = key[i];
    uint32_t p = atomicAdd(&wptr[k >> SHIFT], 1u);
    gkey[p] = k;
    gidx[p] = (uint32_t)i;
}

// K4: per-element in-bin strict-less count -> sorted output + inverse index
__global__ __launch_bounds__(256) void k_rank(const uint32_t* __restrict__ gkey,
                                              const uint32_t* __restrict__ gidx,
                                              const uint32_t* __restrict__ base,
                                              float* __restrict__ out_sorted,
                                              float* __restrict__ out_inv) {
    const int p = blockIdx.x * 256 + threadIdx.x;
    if (p >= N_NODES) return;
    const uint32_t k = gkey[p];
    const uint32_t b = k >> SHIFT;
    const uint32_t s = base[b], e = base[b + 1];
    uint32_t less = 0, eqb = 0;
    for (uint32_t q = s; q < e; ++q) {
        uint32_t k2 = gkey[q];
        less += (k2 < k) ? 1u : 0u;
        eqb  += ((k2 == k) && (q < (uint32_t)p)) ? 1u : 0u;
    }
    out_sorted[s + less + eqb] = k2f(k);   // unique slot (ties broken by grouped pos)
    out_inv[gidx[p]] = (float)(s + less);  // searchsorted-left rank
}

extern "C" void kernel_launch(void* const* d_in, const int* in_sizes, int n_in,
                              void* d_out, int out_size, void* d_ws, size_t ws_size,
                              hipStream_t stream) {
    const float* x = (const float*)d_in[0];   // [500000, 256]
    const float* W = (const float*)d_in[1];   // [64, 256]

    uint32_t* ws32 = (uint32_t*)d_ws;
    float*    wbar = (float*)ws32;              // 256
    uint32_t* key  = ws32 + 256;                // N
    uint32_t* gkey = key  + N_NODES;            // N
    uint32_t* gidx = gkey + N_NODES;            // N
    uint32_t* hist = gidx + N_NODES;            // NB + 1 (becomes base after scan)
    uint32_t* wptr = hist + NB + 1;             // NB
    uint32_t* bsum = wptr + NB;                 // SCAN_NBLK

    float* out_sorted = (float*)d_out;
    float* out_inv    = out_sorted + N_NODES;

    k_prep<<<SCAN_NBLK + 1, 256, 0, stream>>>(W, wbar, hist);
    k_gemv<<<N_NODES / ROWS_PER_BLK, 256, 0, stream>>>(x, wbar, key, hist);
    k_scan1<<<SCAN_NBLK, SCAN_BLK, 0, stream>>>(hist, bsum);
    k_scan23<<<SCAN_NBLK, SCAN_BLK, 0, stream>>>(hist, bsum, wptr);
    k_scatter<<<(N_NODES + 255) / 256, 256, 0, stream>>>(key, wptr, gkey, gidx);
    k_rank<<<(N_NODES + 255) / 256, 256, 0, stream>>>(gkey, gidx, hist, out_sorted, out_inv);
}